// Round 26
// baseline (3426.482 us; speedup 1.0000x reference)
//
#include <hip/hip_runtime.h>
#include <stdint.h>

#define BDIM 4
#define SDIM 2048
#define VDIM 32000
#define DDIM 2048
#define NATK 20
#define BS (BDIM * SDIM)

typedef unsigned long long u64;

// ---------------------------------------------------------------- init best
__global__ void init_best(u64* best) {
    int i = threadIdx.x;
    if (i < NATK) best[i] = 0xFFFFFFFFFFFFFFFFULL;
}

// ---------------------------------------------------------------- rank scan
// mask is INT32 (harness converts bool inputs to int32 — root cause of
// rounds 1-24!). rank[i] = (cumsum(mask)-1) % NATK at masked, 0 else.
__global__ void rank_kernel(const int* __restrict__ mask,
                            int* __restrict__ rank) {
    __shared__ int sdata[256];
    const int b = blockIdx.x;
    const int tid = threadIdx.x;
    const int* mrow = mask + b * SDIM;
    const int s0 = tid * 8;
    int m[8];
    int cnt = 0;
    #pragma unroll
    for (int j = 0; j < 8; ++j) { m[j] = mrow[s0 + j]; cnt += m[j] ? 1 : 0; }
    sdata[tid] = cnt;
    __syncthreads();
    for (int off = 1; off < 256; off <<= 1) {
        int t = (tid >= off) ? sdata[tid - off] : 0;
        __syncthreads();
        sdata[tid] += t;
        __syncthreads();
    }
    int r = sdata[tid] - cnt;  // exclusive prefix of masked count
    int* rrow = rank + b * SDIM;
    #pragma unroll
    for (int j = 0; j < 8; ++j) {
        rrow[s0 + j] = m[j] ? (r % NATK) : 0;
        if (m[j]) r++;
    }
}

// ---------------------------------------------------------------- embeddings
// out0[p] = mask[p] ? attack[rank[p]] : emb[ids[p]]  (exact f32 gather)
__global__ __launch_bounds__(256) void embed_kernel(
        const int* __restrict__ ids, const int* __restrict__ mask,
        const int* __restrict__ rank, const float* __restrict__ attack,
        const float* __restrict__ emb, float* __restrict__ out) {
    const int p = blockIdx.x;
    const float* src = mask[p] ? (attack + (size_t)rank[p] * DDIM)
                               : (emb + (size_t)ids[p] * DDIM);
    const float4* s4 = (const float4*)src;
    float4* dst = (float4*)(out + (size_t)p * DDIM);
    const int t = threadIdx.x;
    dst[t]       = s4[t];
    dst[t + 256] = s4[t + 256];
}

// ---------------------------------------------------------------- NN search
// f32 d^2 argmin winners for the 20 attack rows (verified equal to the
// reference's winners by R25). Ties -> lowest v (np argmin first-index).
__global__ __launch_bounds__(256) void nn_simple(
        const float* __restrict__ attack, const float* __restrict__ emb,
        u64* __restrict__ best) {
    const int gw = (int)((blockIdx.x * 256u + threadIdx.x) >> 6);
    const int lane = threadIdx.x & 63;
    if (gw >= VDIM) return;
    const float* wrow = emb + (size_t)gw * DDIM;

    float acc[NATK];
    #pragma unroll
    for (int k = 0; k < NATK; ++k) acc[k] = 0.f;
    float w2 = 0.f;

    for (int t = 0; t < DDIM / 128; ++t) {
        const int d0 = t * 128 + lane * 2;
        float2 wv = *(const float2*)(wrow + d0);
        w2 = fmaf(wv.x, wv.x, w2);
        w2 = fmaf(wv.y, wv.y, w2);
        #pragma unroll
        for (int k = 0; k < NATK; ++k) {
            float2 qv = *(const float2*)(attack + (size_t)k * DDIM + d0);
            acc[k] = fmaf(qv.x, wv.x, acc[k]);
            acc[k] = fmaf(qv.y, wv.y, acc[k]);
        }
    }

    #pragma unroll
    for (int off = 32; off > 0; off >>= 1) {
        w2 += __shfl_down(w2, off);
        #pragma unroll
        for (int k = 0; k < NATK; ++k) acc[k] += __shfl_down(acc[k], off);
    }

    if (lane == 0) {
        #pragma unroll
        for (int k = 0; k < NATK; ++k) {
            float score = w2 - 2.f * acc[k];  // x2_k const: argmin-invariant
            unsigned int fb = __float_as_uint(score);
            unsigned int key = (fb & 0x80000000u) ? ~fb : (fb | 0x80000000u);
            u64 pk = ((u64)key << 32) | (unsigned int)gw;
            atomicMin(&best[k], pk);
        }
    }
}

// ---------------------------------------------------------------- final ids
// Reference semantics, int32 mask:
//   masked   -> winner[rank[i]]
//   unmasked -> input_ids[i]
__global__ void ids_kernel(const int* __restrict__ ids,
                           const int* __restrict__ mask,
                           const int* __restrict__ rank,
                           const u64* __restrict__ best,
                           float* __restrict__ out_ids) {
    int i = blockIdx.x * blockDim.x + threadIdx.x;
    if (i >= BS) return;
    int id;
    if (mask[i])
        id = (int)(unsigned int)(best[rank[i]] & 0xFFFFFFFFULL);
    else
        id = ids[i];
    out_ids[i] = (float)id;
}

// ---------------------------------------------------------------- launch
extern "C" void kernel_launch(void* const* d_in, const int* in_sizes, int n_in,
                              void* d_out, int out_size, void* d_ws,
                              size_t ws_size, hipStream_t stream) {
    const int* ids = (const int*)d_in[0];
    const int* mask = (const int*)d_in[1];   // bool input -> int32 on device!
    const float* attack = (const float*)d_in[2];
    const float* emb = (const float*)d_in[3];
    float* out = (float*)d_out;

    char* ws = (char*)d_ws;
    int* rank = (int*)ws;            // 32 KB
    u64* best = (u64*)(ws + 32768);  // 160 B

    hipLaunchKernelGGL(init_best, dim3(1), dim3(32), 0, stream, best);
    hipLaunchKernelGGL(rank_kernel, dim3(BDIM), dim3(256), 0, stream, mask, rank);
    hipLaunchKernelGGL(embed_kernel, dim3(BS), dim3(256), 0, stream, ids, mask,
                       rank, attack, emb, out);
    hipLaunchKernelGGL(nn_simple, dim3(VDIM * 64 / 256), dim3(256), 0, stream,
                       attack, emb, best);
    hipLaunchKernelGGL(ids_kernel, dim3((BS + 255) / 256), dim3(256), 0, stream,
                       ids, mask, rank, best, out + (size_t)BS * DDIM);
}